// Round 5
// baseline (100.232 us; speedup 1.0000x reference)
//
#include <hip/hip_runtime.h>
#include <hip/hip_bf16.h>

#define NROWS 8192
#define DDIM  256
#define BM 128
#define BN 128
#define BK 32   // K per step; A|B interleaved in 128B LDS lines -> 16 KB/block

typedef __attribute__((ext_vector_type(4))) float f32x4;
typedef __attribute__((ext_vector_type(8))) short bf16x8;
typedef __attribute__((ext_vector_type(4))) short short4v;

__device__ inline short f2bf(float f) {
    union { float f; unsigned u; } c; c.f = f;
    unsigned u = c.u;
    u += 0x7fffu + ((u >> 16) & 1u);   // round-to-nearest-even
    return (short)(u >> 16);
}

// ---------------- pre-pass: f32 -> bf16 convert + row norms -----------------
__global__ __launch_bounds__(256) void convert_norms_kernel(
    const float* __restrict__ x, const float* __restrict__ y,
    short* __restrict__ xb, short* __restrict__ yb,
    float* __restrict__ xsq, float* __restrict__ ysq) {
    int row  = blockIdx.x * 4 + (threadIdx.x >> 6);
    int lane = threadIdx.x & 63;
    const float* src; short* dstb; float* dstn; int r;
    if (row < NROWS) { r = row;        src = x + (size_t)r * DDIM; dstb = xb + (size_t)r * DDIM; dstn = xsq; }
    else             { r = row - NROWS; src = y + (size_t)r * DDIM; dstb = yb + (size_t)r * DDIM; dstn = ysq; }
    f32x4 v = __builtin_nontemporal_load(&((const f32x4*)src)[lane]);  // read-once
    short4v o;
    #pragma unroll
    for (int j = 0; j < 4; ++j) o[j] = f2bf(v[j]);
    ((short4v*)dstb)[lane] = o;                     // re-read by GEMM: keep cached
    float s = v[0]*v[0] + v[1]*v[1] + v[2]*v[2] + v[3]*v[3];
    #pragma unroll
    for (int off = 32; off > 0; off >>= 1) s += __shfl_xor(s, off, 64);
    if (lane == 0) dstn[r] = s;
}

// ---------------- main GEMM: 16KB LDS (A|B interleaved lines), BK=32 --------
__global__ __launch_bounds__(256, 4) void rbf_gemm_bf16_kernel(
    const char* __restrict__ Xb, const char* __restrict__ Yb,
    const float* __restrict__ xsq, const float* __restrict__ ysq,
    float* __restrict__ out) {
    // 128 lines x 128B: line r = [ A row r, k-bytes 0..63 | B row r, k-bytes 0..63 ]
    // XOR-swizzled within the line by ((r&7)<<4).
    __shared__ char lds[BM * 128];   // 16 KB

    const int tid  = threadIdx.x;
    const int lane = tid & 63;
    const int wid  = tid >> 6;

    // T1 XCD-bijective swizzle: 4096 blocks = 8 XCDs x (32 by x 16 bx).
    const int bid = blockIdx.x;
    const int xcd = bid & 7;
    const int c   = bid >> 3;
    const int by  = (xcd >> 2) * 32 + (c >> 4);
    const int bx  = (xcd & 3)  * 16 + (c & 15);
    const int brow = by * BM;
    const int bcol = bx * BN;
    const int wr = (wid >> 1) * 64;
    const int wc = (wid & 1) * 64;

    // Pre-swizzled global sources (rule #21: linear LDS dest, inverse-swizzled
    // source, swizzled read). Chunk i of this thread lands at LDS byte
    // q = i*4096 + tid*16; line = q>>7, col = q&127; scol = col ^ ((line&7)<<4);
    // scol<64 -> X row (brow+line), k-byte scol; else Y row (bcol+line), scol-64.
    const char* src[4];
    #pragma unroll
    for (int i = 0; i < 4; ++i) {
        const int q    = i * 4096 + tid * 16;
        const int line = q >> 7;
        const int scol = (q & 127) ^ ((line & 7) << 4);
        src[i] = (scol < 64)
            ? Xb + (size_t)(brow + line) * 512 + scol
            : Yb + (size_t)(bcol + line) * 512 + (scol - 64);
    }

    const int swz = (lane & 7) << 4;               // read-side swizzle (row&7 == lane&7)
    const int kq  = (lane >> 4) << 4;              // 16B k-chunk per lane quarter

    f32x4 acc[4][4] = {};

    for (int ks = 0; ks < DDIM / BK; ++ks) {       // 8 steps, 64B of k per row
        #pragma unroll
        for (int i = 0; i < 4; ++i)
            __builtin_amdgcn_global_load_lds(
                (const __attribute__((address_space(1))) void*)(src[i] + ks * 64),
                (__attribute__((address_space(3))) void*)(lds + i * 4096 + wid * 1024),
                16, 0, 0);
        __syncthreads();

        bf16x8 af[4], bf[4];
        #pragma unroll
        for (int m = 0; m < 4; ++m) {
            const int r = wr + m * 16 + (lane & 15);
            af[m] = *(const bf16x8*)(lds + r * 128 + (kq ^ swz));
        }
        #pragma unroll
        for (int n = 0; n < 4; ++n) {
            const int r = wc + n * 16 + (lane & 15);
            bf[n] = *(const bf16x8*)(lds + r * 128 + ((64 + kq) ^ swz));
        }
        #pragma unroll
        for (int m = 0; m < 4; ++m)
            #pragma unroll
            for (int n = 0; n < 4; ++n)
                acc[m][n] = __builtin_amdgcn_mfma_f32_16x16x32_bf16(
                    bf[n], af[m], acc[m][n], 0, 0, 0);   // operand-swapped
        __syncthreads();
    }

    // Epilogue. With swapped operands: D col(lane&15) = X-row index,
    // D row((lane>>4)*4+j) = Y-col index -> each thread's 4 regs are 4
    // CONSECUTIVE output columns -> dwordx4 stores.
    #pragma unroll
    for (int m = 0; m < 4; ++m) {
        const int R  = brow + wr + m * 16 + (lane & 15);
        const float xsv = xsq[R];
        #pragma unroll
        for (int n = 0; n < 4; ++n) {
            const int C = bcol + wc + n * 16 + ((lane >> 4) << 2);
            const f32x4 ysv = *(const f32x4*)&ysq[C];
            f32x4 v;
            #pragma unroll
            for (int j = 0; j < 4; ++j)
                v[j] = __expf(2.0f * acc[m][n][j] - xsv - ysv[j]);
            *(f32x4*)&out[(size_t)R * NROWS + C] = v;
        }
    }
}

// ---------------- fallback (small ws): f32 reg-staging GEMM -----------------
__global__ __launch_bounds__(256) void row_norms_kernel(
    const float* __restrict__ x, const float* __restrict__ y,
    float* __restrict__ sq) {
    int row  = blockIdx.x * 4 + (threadIdx.x >> 6);
    int lane = threadIdx.x & 63;
    const float* src = (row < NROWS) ? (x + (size_t)row * DDIM)
                                     : (y + (size_t)(row - NROWS) * DDIM);
    f32x4 v = ((const f32x4*)src)[lane];
    float s = v[0]*v[0] + v[1]*v[1] + v[2]*v[2] + v[3]*v[3];
    #pragma unroll
    for (int off = 32; off > 0; off >>= 1) s += __shfl_xor(s, off, 64);
    if (lane == 0) sq[row] = s;
}

__global__ __launch_bounds__(256) void rbf_gemm_f32_kernel(
    const float* __restrict__ X, const float* __restrict__ Y,
    const float* __restrict__ xsq, const float* __restrict__ ysq,
    float* __restrict__ out) {
    __shared__ char lds[2 * BM * 64 * 2 * 2];
    char* As = lds;
    char* Bs = lds + BM * 64 * 2;
    const int tid  = threadIdx.x;
    const int lane = tid & 63;
    const int wid  = tid >> 6;
    const int brow = blockIdx.y * BM;
    const int bcol = blockIdx.x * BN;
    const int wr = (wid >> 1) * 64;
    const int wc = (wid & 1) * 64;
    const int srow  = tid >> 1;
    const int shalf = tid & 1;
    const float* aptr = X + (size_t)(brow + srow) * DDIM + shalf * 32;
    const float* bptr = Y + (size_t)(bcol + srow) * DDIM + shalf * 32;
    const int swz = (srow & 7) << 4;
    f32x4 acc[4][4] = {};
    for (int ks = 0; ks < DDIM / 64; ++ks) {
        __syncthreads();
        #pragma unroll
        for (int i = 0; i < 4; ++i) {
            f32x4 a0 = ((const f32x4*)(aptr + ks * 64))[2*i];
            f32x4 a1 = ((const f32x4*)(aptr + ks * 64))[2*i + 1];
            f32x4 b0 = ((const f32x4*)(bptr + ks * 64))[2*i];
            f32x4 b1 = ((const f32x4*)(bptr + ks * 64))[2*i + 1];
            bf16x8 av, bv;
            #pragma unroll
            for (int j = 0; j < 4; ++j) {
                av[j]   = f2bf(a0[j]);  av[4+j] = f2bf(a1[j]);
                bv[j]   = f2bf(b0[j]);  bv[4+j] = f2bf(b1[j]);
            }
            const int cb = shalf * 64 + i * 16;
            *(bf16x8*)(As + srow * 128 + (cb ^ swz)) = av;
            *(bf16x8*)(Bs + srow * 128 + (cb ^ swz)) = bv;
        }
        __syncthreads();
        #pragma unroll
        for (int kk = 0; kk < 2; ++kk) {
            const int kb = kk * 64 + ((lane >> 4) << 4);
            bf16x8 af[4], bf[4];
            #pragma unroll
            for (int m = 0; m < 4; ++m) {
                const int r = wr + m * 16 + (lane & 15);
                af[m] = *(const bf16x8*)(As + r * 128 + (kb ^ ((r & 7) << 4)));
            }
            #pragma unroll
            for (int n = 0; n < 4; ++n) {
                const int cc = wc + n * 16 + (lane & 15);
                bf[n] = *(const bf16x8*)(Bs + cc * 128 + (kb ^ ((cc & 7) << 4)));
            }
            #pragma unroll
            for (int m = 0; m < 4; ++m)
                #pragma unroll
                for (int n = 0; n < 4; ++n)
                    acc[m][n] = __builtin_amdgcn_mfma_f32_16x16x32_bf16(
                        af[m], bf[n], acc[m][n], 0, 0, 0);
        }
    }
    const int r0 = brow + wr + ((lane >> 4) << 2);
    const int c0 = bcol + wc + (lane & 15);
    float xs[4][4];
    #pragma unroll
    for (int m = 0; m < 4; ++m)
        #pragma unroll
        for (int j = 0; j < 4; ++j)
            xs[m][j] = xsq[r0 + m * 16 + j];
    #pragma unroll
    for (int n = 0; n < 4; ++n) {
        const float ys = ysq[c0 + n * 16];
        #pragma unroll
        for (int m = 0; m < 4; ++m) {
            #pragma unroll
            for (int j = 0; j < 4; ++j) {
                const int row = r0 + m * 16 + j;
                const float v = __expf(2.0f * acc[m][n][j] - xs[m][j] - ys);
                out[(size_t)row * NROWS + c0 + n * 16] = v;
            }
        }
    }
}

extern "C" void kernel_launch(void* const* d_in, const int* in_sizes, int n_in,
                              void* d_out, int out_size, void* d_ws, size_t ws_size,
                              hipStream_t stream) {
    const float* x = (const float*)d_in[0];
    const float* y = (const float*)d_in[1];
    float* out = (float*)d_out;

    const size_t xb_bytes = (size_t)NROWS * DDIM * 2;         // 4 MB
    const size_t needed   = 2 * xb_bytes + 2 * NROWS * 4;     // + norms

    if (ws_size >= needed) {
        char*  ws  = (char*)d_ws;
        short* xb  = (short*)ws;
        short* yb  = (short*)(ws + xb_bytes);
        float* xsq = (float*)(ws + 2 * xb_bytes);
        float* ysq = xsq + NROWS;
        convert_norms_kernel<<<dim3(2 * NROWS / 4), dim3(256), 0, stream>>>(
            x, y, xb, yb, xsq, ysq);
        rbf_gemm_bf16_kernel<<<dim3(4096), dim3(256), 0, stream>>>(
            (const char*)xb, (const char*)yb, xsq, ysq, out);
    } else {
        float* sq = (float*)d_ws;
        row_norms_kernel<<<dim3(2 * NROWS / 4), dim3(256), 0, stream>>>(x, y, sq);
        rbf_gemm_f32_kernel<<<dim3(NROWS / BN, NROWS / BM), dim3(256), 0, stream>>>(
            x, y, sq, sq + NROWS, out);
    }
}